// Round 1
// baseline (199.391 us; speedup 1.0000x reference)
//
#include <hip/hip_runtime.h>
#include <cstdint>
#include <cstddef>

#define L_SEQ  2048
#define DMODEL 1024
#define NHEADS 16
#define HDIM   64
#define NQKV   3072

typedef float f32x4 __attribute__((ext_vector_type(4)));
typedef short s16x8 __attribute__((ext_vector_type(8)));

// fp32 -> bf16 round-to-nearest-even (raw bits; finite inputs only)
static __device__ __forceinline__ unsigned short f2bf(float f) {
  unsigned u = __float_as_uint(f);
  return (unsigned short)((u + 0x7fffu + ((u >> 16) & 1u)) >> 16);
}

// async global->LDS, 16B per lane; lds base must be wave-uniform
static __device__ __forceinline__ void gld_lds16(void* lds, const void* g) {
  __builtin_amdgcn_global_load_lds(
      (const __attribute__((address_space(1))) void*)g,
      (__attribute__((address_space(3))) void*)lds, 16, 0, 0);
}

// ---------------------------------------------------------------- convert
__global__ __launch_bounds__(256) void cvt_kernel(
    const float* __restrict__ x, const float* __restrict__ wqkv,
    const float* __restrict__ wout,
    unsigned short* __restrict__ xb, unsigned short* __restrict__ wqkvb,
    unsigned short* __restrict__ woutb) {
  const int NX = L_SEQ * DMODEL / 4;
  const int NW1 = NQKV * DMODEL / 4;
  const int NW2 = DMODEL * DMODEL / 4;
  const int tot = NX + NW1 + NW2;
  for (int i = blockIdx.x * blockDim.x + threadIdx.x; i < tot;
       i += gridDim.x * blockDim.x) {
    const float4* s;
    unsigned short* d;
    int j;
    if (i < NX) { s = (const float4*)x; d = xb; j = i; }
    else if (i < NX + NW1) { s = (const float4*)wqkv; d = wqkvb; j = i - NX; }
    else { s = (const float4*)wout; d = woutb; j = i - NX - NW1; }
    float4 v = s[j];
    ushort4 o;
    o.x = f2bf(v.x); o.y = f2bf(v.y); o.z = f2bf(v.z); o.w = f2bf(v.w);
    *(ushort4*)(d + 4 * (size_t)j) = o;
  }
}

// ------------------------------------------------- shared 128x128 GEMM core
// C[m][n] = sum_k A[m][k] * Bt[n][k]; A: Mx(KDIM), Bt: Nx(KDIM), bf16 bits.
// Block 256 thr (4 waves, 2x2 of 64x64), BK=32, single-buffer LDS staging.
template <int KDIM>
static __device__ __forceinline__ void gemm_bt_core(
    const unsigned short* __restrict__ A, const unsigned short* __restrict__ Bt,
    unsigned short* As, unsigned short* Bs, int bm, int bn, f32x4 acc[4][4]) {
  const int tid = threadIdx.x;
  const int lane = tid & 63;
  const int wave = tid >> 6;
  const int g = lane >> 4;
  const int li = lane & 15;
  const int wm = (wave >> 1) * 64;
  const int wn = (wave & 1) * 64;
  const int arow = tid >> 2;           // 0..63
  const int acolb = (tid & 3) << 4;    // byte offset in 64B row chunk
  const char* gA = (const char*)A + (size_t)(bm * 128 + arow) * (KDIM * 2) + acolb;
  const char* gB = (const char*)Bt + (size_t)(bn * 128 + arow) * (KDIM * 2) + acolb;
  char* lA = (char*)As + wave * 1024;
  char* lB = (char*)Bs + wave * 1024;
  const size_t half = (size_t)64 * KDIM * 2;
  for (int kt = 0; kt < KDIM; kt += 32) {
    __syncthreads();  // prev iter's ds_reads done before overwrite
    gld_lds16(lA, gA + kt * 2);
    gld_lds16(lA + 4096, gA + half + kt * 2);
    gld_lds16(lB, gB + kt * 2);
    gld_lds16(lB + 4096, gB + half + kt * 2);
    __syncthreads();  // staging complete (vmcnt drained by barrier)
    const s16x8* Av = (const s16x8*)As;
    const s16x8* Bv = (const s16x8*)Bs;
    s16x8 af[4], bfv[4];
#pragma unroll
    for (int mt = 0; mt < 4; ++mt) af[mt] = Av[(wm + mt * 16 + li) * 4 + g];
#pragma unroll
    for (int nt = 0; nt < 4; ++nt) bfv[nt] = Bv[(wn + nt * 16 + li) * 4 + g];
#pragma unroll
    for (int mt = 0; mt < 4; ++mt)
#pragma unroll
      for (int nt = 0; nt < 4; ++nt)
        acc[mt][nt] = __builtin_amdgcn_mfma_f32_16x16x32_bf16(
            af[mt], bfv[nt], acc[mt][nt], 0, 0, 0);
  }
}

// ------------------------------------------------------------- QKV GEMM
// A = xb (2048x1024), Bt = wqkvb (3072x1024). Scatters to Q (x0.125), K, V^T.
__global__ __launch_bounds__(256, 2) void gemm_qkv_k(
    const unsigned short* __restrict__ A, const unsigned short* __restrict__ Bt,
    const float* __restrict__ bqkv, unsigned short* __restrict__ Qb,
    unsigned short* __restrict__ Kb, unsigned short* __restrict__ Vt) {
  __shared__ alignas(16) unsigned short As[128 * 32], Bs[128 * 32];
  f32x4 acc[4][4] = {};
  gemm_bt_core<DMODEL>(A, Bt, As, Bs, blockIdx.x, blockIdx.y, acc);
  const int lane = threadIdx.x & 63, wave = threadIdx.x >> 6;
  const int g = lane >> 4, li = lane & 15;
  const int wm = (wave >> 1) * 64, wn = (wave & 1) * 64;
#pragma unroll
  for (int mt = 0; mt < 4; ++mt)
#pragma unroll
    for (int nt = 0; nt < 4; ++nt)
#pragma unroll
      for (int r = 0; r < 4; ++r) {
        int i = blockIdx.x * 128 + wm + mt * 16 + 4 * g + r;
        int n = blockIdx.y * 128 + wn + nt * 16 + li;
        float v = acc[mt][nt][r] + bqkv[n];
        int s = n >> 10;            // 0=q 1=k 2=v (uniform per block)
        int h = (n >> 6) & 15;
        int d = n & 63;
        if (s == 0)      Qb[(((size_t)h * L_SEQ + i) << 6) + d] = f2bf(v * 0.125f);
        else if (s == 1) Kb[(((size_t)h * L_SEQ + i) << 6) + d] = f2bf(v);
        else             Vt[(size_t)(h * 64 + d) * L_SEQ + i] = f2bf(v);
      }
}

// ------------------------------------------------------------- attention
// grid (32 i-tiles, 16 heads); 4 waves x 16 rows; flash over 64-wide j-tiles.
__global__ __launch_bounds__(256, 2) void attn_k(
    const unsigned short* __restrict__ Qb, const unsigned short* __restrict__ Kb,
    const unsigned short* __restrict__ Vt, const float* __restrict__ bias,
    const float* __restrict__ gate, unsigned short* __restrict__ AO) {
  __shared__ alignas(16) char plds[4 * 2048];  // 16x64 bf16 P tile per wave
  const int h = blockIdx.y;
  const int tid = threadIdx.x, lane = tid & 63, wave = tid >> 6;
  const int g = lane >> 4, li = lane & 15;
  const int i0 = blockIdx.x * 64 + wave * 16;
  char* myP = plds + wave * 2048;
  const s16x8* Qv = (const s16x8*)(Qb + (((size_t)h * L_SEQ + i0) << 6));
  const s16x8 qf0 = Qv[li * 8 + g];
  const s16x8 qf1 = Qv[li * 8 + 4 + g];
  const float gh = gate[h];
  const float* bh = bias + (size_t)h * L_SEQ * L_SEQ;
  f32x4 accO[4] = {};
  float mrow[4], lrow[4];
#pragma unroll
  for (int r = 0; r < 4; ++r) { mrow[r] = -1e30f; lrow[r] = 0.f; }

  for (int j0 = 0; j0 < L_SEQ; j0 += 64) {
    const s16x8* Kv = (const s16x8*)(Kb + (((size_t)h * L_SEQ + j0) << 6));
    f32x4 s[4];
#pragma unroll
    for (int nt = 0; nt < 4; ++nt) {
      s16x8 k0 = Kv[(nt * 16 + li) * 8 + g];
      s16x8 k1 = Kv[(nt * 16 + li) * 8 + 4 + g];
      f32x4 z = {0.f, 0.f, 0.f, 0.f};
      z = __builtin_amdgcn_mfma_f32_16x16x32_bf16(qf0, k0, z, 0, 0, 0);
      z = __builtin_amdgcn_mfma_f32_16x16x32_bf16(qf1, k1, z, 0, 0, 0);
      s[nt] = z;
    }
    // + gate*pair_bias (D layout: row = 4g+r, col = nt*16+li)
#pragma unroll
    for (int nt = 0; nt < 4; ++nt)
#pragma unroll
      for (int r = 0; r < 4; ++r)
        s[nt][r] = fmaf(gh,
                        bh[(size_t)(i0 + 4 * g + r) * L_SEQ + j0 + nt * 16 + li],
                        s[nt][r]);
    // online softmax: row stats live across the 16 lanes of each l>>4 group
    float corr[4], psum[4];
#pragma unroll
    for (int r = 0; r < 4; ++r) {
      float t = fmaxf(fmaxf(s[0][r], s[1][r]), fmaxf(s[2][r], s[3][r]));
      t = fmaxf(t, __shfl_xor(t, 1));
      t = fmaxf(t, __shfl_xor(t, 2));
      t = fmaxf(t, __shfl_xor(t, 4));
      t = fmaxf(t, __shfl_xor(t, 8));
      float mn = fmaxf(mrow[r], t);
      corr[r] = __expf(mrow[r] - mn);
      mrow[r] = mn;
      psum[r] = 0.f;
    }
#pragma unroll
    for (int nt = 0; nt < 4; ++nt)
#pragma unroll
      for (int r = 0; r < 4; ++r) {
        float p = __expf(s[nt][r] - mrow[r]);
        s[nt][r] = p;
        psum[r] += p;
      }
#pragma unroll
    for (int r = 0; r < 4; ++r) {
      float t = psum[r];
      t += __shfl_xor(t, 1);
      t += __shfl_xor(t, 2);
      t += __shfl_xor(t, 4);
      t += __shfl_xor(t, 8);
      lrow[r] = lrow[r] * corr[r] + t;
    }
#pragma unroll
    for (int dt = 0; dt < 4; ++dt)
#pragma unroll
      for (int r = 0; r < 4; ++r) accO[dt][r] *= corr[r];
    // P (bf16) -> LDS, XOR-swizzled rows to kill ds_read_b128 bank conflicts
#pragma unroll
    for (int nt = 0; nt < 4; ++nt)
#pragma unroll
      for (int r = 0; r < 4; ++r) {
        int row = 4 * g + r, col = nt * 16 + li;
        unsigned b = (unsigned)(row * 128 + col * 2) ^ (unsigned)((row & 7) << 4);
        *(unsigned short*)(myP + b) = f2bf(s[nt][r]);
      }
    asm volatile("s_waitcnt lgkmcnt(0)" ::: "memory");
    unsigned b0 = ((unsigned)(li * 128 + 16 * g)) ^ (unsigned)((li & 7) << 4);
    unsigned b1 = ((unsigned)(li * 128 + 64 + 16 * g)) ^ (unsigned)((li & 7) << 4);
    s16x8 pa0 = *(const s16x8*)(myP + b0);
    s16x8 pa1 = *(const s16x8*)(myP + b1);
#pragma unroll
    for (int dt = 0; dt < 4; ++dt) {
      size_t vb = (size_t)(h * 64 + dt * 16 + li) * L_SEQ + j0;
      s16x8 v0 = *(const s16x8*)(Vt + vb + 8 * g);
      s16x8 v1 = *(const s16x8*)(Vt + vb + 32 + 8 * g);
      accO[dt] = __builtin_amdgcn_mfma_f32_16x16x32_bf16(pa0, v0, accO[dt], 0, 0, 0);
      accO[dt] = __builtin_amdgcn_mfma_f32_16x16x32_bf16(pa1, v1, accO[dt], 0, 0, 0);
    }
  }
#pragma unroll
  for (int dt = 0; dt < 4; ++dt)
#pragma unroll
    for (int r = 0; r < 4; ++r) {
      int i = i0 + 4 * g + r;
      int d = dt * 16 + li;
      AO[(size_t)i * DMODEL + h * 64 + d] = f2bf(accO[dt][r] / lrow[r]);
    }
}

// ------------------------------------------------------------- out proj
__global__ __launch_bounds__(256, 2) void gemm_out_k(
    const unsigned short* __restrict__ A, const unsigned short* __restrict__ Bt,
    const float* __restrict__ bout, float* __restrict__ out) {
  __shared__ alignas(16) unsigned short As[128 * 32], Bs[128 * 32];
  f32x4 acc[4][4] = {};
  gemm_bt_core<DMODEL>(A, Bt, As, Bs, blockIdx.x, blockIdx.y, acc);
  const int lane = threadIdx.x & 63, wave = threadIdx.x >> 6;
  const int g = lane >> 4, li = lane & 15;
  const int wm = (wave >> 1) * 64, wn = (wave & 1) * 64;
#pragma unroll
  for (int mt = 0; mt < 4; ++mt)
#pragma unroll
    for (int nt = 0; nt < 4; ++nt)
#pragma unroll
      for (int r = 0; r < 4; ++r) {
        int i = blockIdx.x * 128 + wm + mt * 16 + 4 * g + r;
        int n = blockIdx.y * 128 + wn + nt * 16 + li;
        out[(size_t)i * DMODEL + n] = acc[mt][nt][r] + bout[n];
      }
}

// ---------------------------------------------------------------- launch
extern "C" void kernel_launch(void* const* d_in, const int* in_sizes, int n_in,
                              void* d_out, int out_size, void* d_ws,
                              size_t ws_size, hipStream_t stream) {
  const float* x = (const float*)d_in[0];
  const float* pb = (const float*)d_in[1];
  const float* gate = (const float*)d_in[2];
  const float* wqkv = (const float*)d_in[3];
  const float* bqkv = (const float*)d_in[4];
  const float* wout = (const float*)d_in[5];
  const float* bout = (const float*)d_in[6];

  unsigned short* ws = (unsigned short*)d_ws;
  unsigned short* xb = ws;
  unsigned short* wqkvb = xb + (size_t)L_SEQ * DMODEL;
  unsigned short* woutb = wqkvb + (size_t)NQKV * DMODEL;
  unsigned short* Qb = woutb + (size_t)DMODEL * DMODEL;
  unsigned short* Kb = Qb + (size_t)NHEADS * L_SEQ * HDIM;
  unsigned short* Vt = Kb + (size_t)NHEADS * L_SEQ * HDIM;
  unsigned short* AO = Vt + (size_t)NHEADS * L_SEQ * HDIM;

  cvt_kernel<<<1024, 256, 0, stream>>>(x, wqkv, wout, xb, wqkvb, woutb);
  gemm_qkv_k<<<dim3(16, 24), 256, 0, stream>>>(xb, wqkvb, bqkv, Qb, Kb, Vt);
  attn_k<<<dim3(32, 16), 256, 0, stream>>>(Qb, Kb, Vt, pb, gate, AO);
  gemm_out_k<<<dim3(16, 8), 256, 0, stream>>>(AO, woutb, bout, (float*)d_out);
}